// Round 1
// baseline (451.941 us; speedup 1.0000x reference)
//
#include <hip/hip_runtime.h>
#include <math.h>

// ============================================================================
// PCT offset-attention block, fp32 baseline with algebraic collapse:
//   G_b = X_b^T X_b                       (k1, big: 4.3 GMAC)
//   E_b = Wq G_b Wq^T                     (k2,k3: tiny 256^3 per batch)
//   A_b = colL1(rowsoftmax(E_b))          (k4a,k4b)
//   P_b = A_b Wt^T                        (k5)
//   W2_b = Wt^T - Wv^T P_b ; b2_b = bt - bv^T P_b   (k6, k6b)
//   t_b  = X_b W2_b + b2_b   (+BN partial sums)     (k7, big: 4.3 GMAC)
//   BN stats (k8); out = x + relu(gamma*that+beta)  (k9, elementwise)
// ============================================================================

#define B_ 16
#define N_ 4096
#define C_ 256
#define M_ (B_*N_)
#define TS 64
#define PAD 68   // 68*4 = 272 B row stride, keeps float4 (16B) alignment
#define BN_EPS 1e-5f

// ---- ws layout (float offsets), total 8393728 floats ~= 33.6 MB ----
#define OFF_GP   ((size_t)0)        // 4 slabs * 16 b * 256*256 (partial Grams)
#define OFF_T    ((size_t)4194304)  // 16 * 256*256
#define OFF_E    ((size_t)5242880)  // E, then A in-place
#define OFF_P    ((size_t)6291456)
#define OFF_W2   ((size_t)7340032)
#define OFF_B2   ((size_t)8388608)  // 16*256
#define OFF_BNS  ((size_t)8392704)  // 256
#define OFF_BNQ  ((size_t)8392960)  // 256
#define OFF_MEAN ((size_t)8393216)  // 256
#define OFF_ISTD ((size_t)8393472)  // 256

// ---------------- shared 64x64x64 fp32 microkernel pieces -------------------

// natural copy: lds[k][m] = src[(r0+k)*256 + c0+m]
__device__ __forceinline__ void load_tile_N(const float* __restrict__ src, int r0, int c0,
                                            float (*lds)[PAD], int t) {
#pragma unroll
  for (int p = 0; p < 4; ++p) {
    int slot = t + (p << 8);
    int r = slot >> 4, c4 = (slot & 15) << 2;
    *(float4*)&lds[r][c4] = *(const float4*)(src + (size_t)(r0 + r) * C_ + c0 + c4);
  }
}

// transposed copy: lds[k][m] = src[(r0+m)*256 + c0+k]
__device__ __forceinline__ void load_tile_T(const float* __restrict__ src, int r0, int c0,
                                            float (*lds)[PAD], int t) {
#pragma unroll
  for (int p = 0; p < 4; ++p) {
    int slot = t + (p << 8);
    int r = slot >> 4, c4 = (slot & 15) << 2;
    float4 v = *(const float4*)(src + (size_t)(r0 + r) * C_ + c0 + c4);
    lds[c4 + 0][r] = v.x;
    lds[c4 + 1][r] = v.y;
    lds[c4 + 2][r] = v.z;
    lds[c4 + 3][r] = v.w;
  }
}

__device__ __forceinline__ void mk64(const float (*Al)[PAD], const float (*Bl)[PAD],
                                     int tr, int tc, float acc[4][4]) {
#pragma unroll 8
  for (int kk = 0; kk < TS; ++kk) {
    float4 a = *(const float4*)&Al[kk][tr << 2];
    float4 b = *(const float4*)&Bl[kk][tc << 2];
    acc[0][0] = fmaf(a.x, b.x, acc[0][0]); acc[0][1] = fmaf(a.x, b.y, acc[0][1]);
    acc[0][2] = fmaf(a.x, b.z, acc[0][2]); acc[0][3] = fmaf(a.x, b.w, acc[0][3]);
    acc[1][0] = fmaf(a.y, b.x, acc[1][0]); acc[1][1] = fmaf(a.y, b.y, acc[1][1]);
    acc[1][2] = fmaf(a.y, b.z, acc[1][2]); acc[1][3] = fmaf(a.y, b.w, acc[1][3]);
    acc[2][0] = fmaf(a.z, b.x, acc[2][0]); acc[2][1] = fmaf(a.z, b.y, acc[2][1]);
    acc[2][2] = fmaf(a.z, b.z, acc[2][2]); acc[2][3] = fmaf(a.z, b.w, acc[2][3]);
    acc[3][0] = fmaf(a.w, b.x, acc[3][0]); acc[3][1] = fmaf(a.w, b.y, acc[3][1]);
    acc[3][2] = fmaf(a.w, b.z, acc[3][2]); acc[3][3] = fmaf(a.w, b.w, acc[3][3]);
  }
}

// ---------------- k0: zero BN accumulators ----------------------------------
__global__ void k0_zero(float* __restrict__ ws) {
  ws[OFF_BNS + threadIdx.x] = 0.0f;  // 512 threads cover BNS(256)+BNQ(256)
}

// ---------------- k1: partial Grams, symmetry-halved ------------------------
// grid (10 uppertri tiles, 4 n-chunks, 16 b). Gp[s][b] = X_chunk^T X_chunk.
__global__ __launch_bounds__(256) void k1_gram(const float* __restrict__ x,
                                               float* __restrict__ ws) {
  const int idx = blockIdx.x, s = blockIdx.y, b = blockIdx.z;
  // upper-triangle tile map for 4x4: idx -> (te, tf), te <= tf
  int te, tf;
  if (idx < 4)      { te = 0; tf = idx; }
  else if (idx < 7) { te = 1; tf = idx - 3; }
  else if (idx < 9) { te = 2; tf = idx - 5; }
  else              { te = 3; tf = 3; }
  const int e0 = te * TS, f0 = tf * TS;
  const int t = threadIdx.x, tr = t >> 4, tc = t & 15;
  __shared__ float Al[TS][PAD], Bl[TS][PAD];
  float acc[4][4] = {};
  const float* xb = x + (size_t)b * N_ * C_;
  const int n0 = s << 10;
  for (int nc = 0; nc < 1024; nc += TS) {
    load_tile_N(xb, n0 + nc, e0, Al, t);
    load_tile_N(xb, n0 + nc, f0, Bl, t);
    __syncthreads();
    mk64(Al, Bl, tr, tc, acc);
    __syncthreads();
  }
  float* gp = ws + OFF_GP + ((size_t)s * B_ + b) * (C_ * C_);
#pragma unroll
  for (int i = 0; i < 4; ++i) {
    float4 v = make_float4(acc[i][0], acc[i][1], acc[i][2], acc[i][3]);
    *(float4*)(gp + (size_t)(e0 + (tr << 2) + i) * C_ + f0 + (tc << 2)) = v;
  }
  if (te != tf) {  // mirror into lower tile
#pragma unroll
    for (int i = 0; i < 4; ++i)
#pragma unroll
      for (int j = 0; j < 4; ++j)
        gp[(size_t)(f0 + (tc << 2) + j) * C_ + e0 + (tr << 2) + i] = acc[i][j];
  }
}

// ---------------- k2: T = G * Wq^T  (G = sum of 4 symmetric partials) -------
__global__ __launch_bounds__(256) void k2_T(const float* __restrict__ Wq,
                                            float* __restrict__ ws) {
  const int tile = blockIdx.x, b = blockIdx.y;
  const int e0 = (tile >> 2) * TS, d0 = (tile & 3) * TS;
  const int t = threadIdx.x, tr = t >> 4, tc = t & 15;
  __shared__ float Al[TS][PAD], Bl[TS][PAD];
  float acc[4][4] = {};
  const float* gp = ws + OFF_GP + (size_t)b * (C_ * C_);  // slab stride 1048576
  for (int k0 = 0; k0 < C_; k0 += TS) {
    // Al[kk=f][e] = G[k0+kk][e0+e]  (G symmetric, partials symmetric -> natural rows)
#pragma unroll
    for (int p = 0; p < 4; ++p) {
      int slot = t + (p << 8);
      int r = slot >> 4, c4 = (slot & 15) << 2;
      size_t off = (size_t)(k0 + r) * C_ + e0 + c4;
      float4 v0 = *(const float4*)(gp + off);
      float4 v1 = *(const float4*)(gp + 1048576 + off);
      float4 v2 = *(const float4*)(gp + 2097152 + off);
      float4 v3 = *(const float4*)(gp + 3145728 + off);
      float4 v = make_float4(v0.x + v1.x + v2.x + v3.x, v0.y + v1.y + v2.y + v3.y,
                             v0.z + v1.z + v2.z + v3.z, v0.w + v1.w + v2.w + v3.w);
      *(float4*)&Al[r][c4] = v;
    }
    load_tile_T(Wq, d0, k0, Bl, t);  // Bl[kk=f][d] = Wq[d0+d][k0+kk]
    __syncthreads();
    mk64(Al, Bl, tr, tc, acc);
    __syncthreads();
  }
  float* T = ws + OFF_T + ((size_t)b << 16);
#pragma unroll
  for (int i = 0; i < 4; ++i) {
    float4 v = make_float4(acc[i][0], acc[i][1], acc[i][2], acc[i][3]);
    *(float4*)(T + (size_t)(e0 + (tr << 2) + i) * C_ + d0 + (tc << 2)) = v;
  }
}

// ---------------- k3: E = Wq * T --------------------------------------------
__global__ __launch_bounds__(256) void k3_E(const float* __restrict__ Wq,
                                            float* __restrict__ ws) {
  const int tile = blockIdx.x, b = blockIdx.y;
  const int c0 = (tile >> 2) * TS, d0 = (tile & 3) * TS;
  const int t = threadIdx.x, tr = t >> 4, tc = t & 15;
  __shared__ float Al[TS][PAD], Bl[TS][PAD];
  float acc[4][4] = {};
  const float* T = ws + OFF_T + ((size_t)b << 16);
  for (int k0 = 0; k0 < C_; k0 += TS) {
    load_tile_T(Wq, c0, k0, Al, t);  // Al[kk=e][c] = Wq[c0+c][k0+kk]
    load_tile_N(T, k0, d0, Bl, t);   // Bl[kk=e][d] = T[k0+kk][d0+d]
    __syncthreads();
    mk64(Al, Bl, tr, tc, acc);
    __syncthreads();
  }
  float* E = ws + OFF_E + ((size_t)b << 16);
#pragma unroll
  for (int i = 0; i < 4; ++i) {
    float4 v = make_float4(acc[i][0], acc[i][1], acc[i][2], acc[i][3]);
    *(float4*)(E + (size_t)(c0 + (tr << 2) + i) * C_ + d0 + (tc << 2)) = v;
  }
}

// ---------------- k4a: row softmax (in place), one block per row ------------
__global__ __launch_bounds__(256) void k4a_softmax(float* __restrict__ E) {
  const int row = blockIdx.x, b = blockIdx.y;
  float* e = E + ((size_t)b << 16) + (size_t)row * C_;
  const int t = threadIdx.x, lane = t & 63, wid = t >> 6;
  __shared__ float rmax[4], rsum[4];
  float v = e[t];
  float m = v;
#pragma unroll
  for (int off = 32; off; off >>= 1) m = fmaxf(m, __shfl_xor(m, off, 64));
  if (lane == 0) rmax[wid] = m;
  __syncthreads();
  m = fmaxf(fmaxf(rmax[0], rmax[1]), fmaxf(rmax[2], rmax[3]));
  float ex = expf(v - m);
  float s = ex;
#pragma unroll
  for (int off = 32; off; off >>= 1) s += __shfl_xor(s, off, 64);
  if (lane == 0) rsum[wid] = s;
  __syncthreads();
  s = rsum[0] + rsum[1] + rsum[2] + rsum[3];
  e[t] = ex / s;
}

// ---------------- k4b: L1 normalize along columns (dim c) -------------------
__global__ __launch_bounds__(256) void k4b_l1(float* __restrict__ A) {
  const int b = blockIdx.x, d = threadIdx.x;
  float* a = A + ((size_t)b << 16);
  float s = 0.0f;
  for (int c = 0; c < C_; ++c) s += a[(size_t)c * C_ + d];
  float inv = 1.0f / (1e-9f + s);
  for (int c = 0; c < C_; ++c) a[(size_t)c * C_ + d] *= inv;
}

// ---------------- k5: P = A * Wt^T ------------------------------------------
__global__ __launch_bounds__(256) void k5_P(const float* __restrict__ Wt,
                                            float* __restrict__ ws) {
  const int tile = blockIdx.x, b = blockIdx.y;
  const int c0 = (tile >> 2) * TS, o0 = (tile & 3) * TS;
  const int t = threadIdx.x, tr = t >> 4, tc = t & 15;
  __shared__ float Al[TS][PAD], Bl[TS][PAD];
  float acc[4][4] = {};
  const float* A = ws + OFF_E + ((size_t)b << 16);
  for (int k0 = 0; k0 < C_; k0 += TS) {
    load_tile_T(A, c0, k0, Al, t);   // Al[kk=j][c] = A[c0+c][k0+kk]
    load_tile_T(Wt, o0, k0, Bl, t);  // Bl[kk=j][o] = Wt[o0+o][k0+kk]
    __syncthreads();
    mk64(Al, Bl, tr, tc, acc);
    __syncthreads();
  }
  float* P = ws + OFF_P + ((size_t)b << 16);
#pragma unroll
  for (int i = 0; i < 4; ++i) {
    float4 v = make_float4(acc[i][0], acc[i][1], acc[i][2], acc[i][3]);
    *(float4*)(P + (size_t)(c0 + (tr << 2) + i) * C_ + o0 + (tc << 2)) = v;
  }
}

// ---------------- k6: W2 = Wt^T - Wv^T * P ----------------------------------
__global__ __launch_bounds__(256) void k6_W2(const float* __restrict__ Wv,
                                             const float* __restrict__ Wt,
                                             float* __restrict__ ws) {
  const int tile = blockIdx.x, b = blockIdx.y;
  const int e0 = (tile >> 2) * TS, o0 = (tile & 3) * TS;
  const int t = threadIdx.x, tr = t >> 4, tc = t & 15;
  __shared__ float Al[TS][PAD], Bl[TS][PAD];
  float acc[4][4] = {};
  const float* P = ws + OFF_P + ((size_t)b << 16);
  for (int k0 = 0; k0 < C_; k0 += TS) {
    load_tile_N(Wv, k0, e0, Al, t);  // Al[kk=c][e] = Wv[k0+kk][e0+e]
    load_tile_N(P, k0, o0, Bl, t);   // Bl[kk=c][o] = P[k0+kk][o0+o]
    __syncthreads();
    mk64(Al, Bl, tr, tc, acc);
    __syncthreads();
  }
  float* W2 = ws + OFF_W2 + ((size_t)b << 16);
#pragma unroll
  for (int i = 0; i < 4; ++i) {
    int e = e0 + (tr << 2) + i;
#pragma unroll
    for (int j = 0; j < 4; ++j) {
      int o = o0 + (tc << 2) + j;
      W2[(size_t)e * C_ + o] = Wt[(size_t)o * C_ + e] - acc[i][j];
    }
  }
}

// ---------------- k6b: b2 = bt - bv^T * P -----------------------------------
__global__ __launch_bounds__(256) void k6b_b2(const float* __restrict__ bv,
                                              const float* __restrict__ bt,
                                              float* __restrict__ ws) {
  const int b = blockIdx.x, o = threadIdx.x;
  const float* P = ws + OFF_P + ((size_t)b << 16);
  float s = 0.0f;
  for (int c = 0; c < C_; ++c) s += bv[c] * P[(size_t)c * C_ + o];
  ws[OFF_B2 + (size_t)b * C_ + o] = bt[o] - s;
}

// ---------------- k7: t = X * W2 + b2, write to d_out, BN partials ----------
__global__ __launch_bounds__(256) void k7_gemm(const float* __restrict__ x,
                                               float* __restrict__ ws,
                                               float* __restrict__ tout) {
  const int o0 = blockIdx.x * TS, n0 = blockIdx.y * TS, b = blockIdx.z;
  const int t = threadIdx.x, tr = t >> 4, tc = t & 15;
  __shared__ float Al[TS][PAD], Bl[TS][PAD];
  float acc[4][4] = {};
  const float* xb = x + (size_t)b * N_ * C_;
  const float* W2 = ws + OFF_W2 + ((size_t)b << 16);
  for (int k0 = 0; k0 < C_; k0 += TS) {
    load_tile_T(xb, n0, k0, Al, t);  // Al[kk=e][n] = X[n0+n][k0+kk]
    load_tile_N(W2, k0, o0, Bl, t);  // Bl[kk=e][o] = W2[k0+kk][o0+o]
    __syncthreads();
    mk64(Al, Bl, tr, tc, acc);
    __syncthreads();
  }
  const float4 b2v = *(const float4*)(ws + OFF_B2 + (size_t)b * C_ + o0 + (tc << 2));
  const float bb[4] = {b2v.x, b2v.y, b2v.z, b2v.w};
  float cs[4] = {}, cq[4] = {};
#pragma unroll
  for (int i = 0; i < 4; ++i) {
    float4 v;
    float* vp = (float*)&v;
#pragma unroll
    for (int j = 0; j < 4; ++j) {
      float val = acc[i][j] + bb[j];
      vp[j] = val;
      cs[j] += val;
      cq[j] += val * val;
    }
    *(float4*)(tout + ((size_t)b * N_ + n0 + (tr << 2) + i) * C_ + o0 + (tc << 2)) = v;
  }
  // block-level per-column reduction (reuse LDS tiles), then one atomic per col
  float* ls = &Al[0][0];
  float* lq = &Bl[0][0];
  __syncthreads();
#pragma unroll
  for (int j = 0; j < 4; ++j) {
    ls[tr * 64 + (tc << 2) + j] = cs[j];
    lq[tr * 64 + (tc << 2) + j] = cq[j];
  }
  __syncthreads();
  if (t < 64) {
    float s = 0.0f, q = 0.0f;
#pragma unroll
    for (int r = 0; r < 16; ++r) {
      s += ls[r * 64 + t];
      q += lq[r * 64 + t];
    }
    atomicAdd(ws + OFF_BNS + o0 + t, s);
    atomicAdd(ws + OFF_BNQ + o0 + t, q);
  }
}

// ---------------- k8: BN stats ----------------------------------------------
__global__ void k8_stats(float* __restrict__ ws) {
  const int c = threadIdx.x;
  float mean = ws[OFF_BNS + c] * (1.0f / (float)M_);
  float var = ws[OFF_BNQ + c] * (1.0f / (float)M_) - mean * mean;
  ws[OFF_MEAN + c] = mean;
  ws[OFF_ISTD + c] = rsqrtf(var + BN_EPS);
}

// ---------------- k9: out = x + relu(gamma*(t-mean)*istd + beta), in place --
__global__ __launch_bounds__(256) void k9_final(const float* __restrict__ x,
                                                const float* __restrict__ gamma,
                                                const float* __restrict__ beta,
                                                const float* __restrict__ ws,
                                                float* __restrict__ out) {
  const size_t i4 = ((size_t)blockIdx.x * 256 + threadIdx.x) << 2;
  const int c0 = (int)(i4 & 255);
  float4 tv = *(const float4*)(out + i4);
  float4 xv = *(const float4*)(x + i4);
  float4 g = *(const float4*)(gamma + c0);
  float4 be = *(const float4*)(beta + c0);
  float4 mn = *(const float4*)(ws + OFF_MEAN + c0);
  float4 is = *(const float4*)(ws + OFF_ISTD + c0);
  float4 r;
  r.x = xv.x + fmaxf(0.0f, fmaf(g.x, (tv.x - mn.x) * is.x, be.x));
  r.y = xv.y + fmaxf(0.0f, fmaf(g.y, (tv.y - mn.y) * is.y, be.y));
  r.z = xv.z + fmaxf(0.0f, fmaf(g.z, (tv.z - mn.z) * is.z, be.z));
  r.w = xv.w + fmaxf(0.0f, fmaf(g.w, (tv.w - mn.w) * is.w, be.w));
  *(float4*)(out + i4) = r;
}

// ============================================================================
extern "C" void kernel_launch(void* const* d_in, const int* in_sizes, int n_in,
                              void* d_out, int out_size, void* d_ws, size_t ws_size,
                              hipStream_t stream) {
  const float* x = (const float*)d_in[1];   // d_in[0] = xyz, unused by reference
  const float* Wq = (const float*)d_in[2];
  const float* Wv = (const float*)d_in[3];
  const float* bv = (const float*)d_in[4];
  const float* Wt = (const float*)d_in[5];
  const float* bt = (const float*)d_in[6];
  const float* gamma = (const float*)d_in[7];
  const float* beta = (const float*)d_in[8];
  float* out = (float*)d_out;
  float* ws = (float*)d_ws;

  k0_zero<<<1, 512, 0, stream>>>(ws);
  k1_gram<<<dim3(10, 4, B_), 256, 0, stream>>>(x, ws);
  k2_T<<<dim3(16, B_), 256, 0, stream>>>(Wq, ws);
  k3_E<<<dim3(16, B_), 256, 0, stream>>>(Wq, ws);
  k4a_softmax<<<dim3(C_, B_), 256, 0, stream>>>(ws + OFF_E);
  k4b_l1<<<B_, 256, 0, stream>>>(ws + OFF_E);
  k5_P<<<dim3(16, B_), 256, 0, stream>>>(Wt, ws);
  k6_W2<<<dim3(16, B_), 256, 0, stream>>>(Wv, Wt, ws);
  k6b_b2<<<B_, 256, 0, stream>>>(bv, bt, ws);
  k7_gemm<<<dim3(4, 64, B_), 256, 0, stream>>>(x, ws, out);
  k8_stats<<<1, 256, 0, stream>>>(ws);
  k9_final<<<(M_ * C_) / 1024, 256, 0, stream>>>(x, gamma, beta, ws, out);
}

// Round 2
// 337.686 us; speedup vs baseline: 1.3383x; 1.3383x over previous
//
#include <hip/hip_runtime.h>
#include <math.h>

// ============================================================================
// PCT offset-attention block:
//   G_b = X_b^T X_b                    (k1: bf16 MFMA, numerically safe — softmax saturated)
//   E_b = Wq G_b Wq^T                  (k2,k3: fp32 vector, tiny)
//   A_b = colL1(rowsoftmax(E_b))       (k4a,k4b)
//   P_b = A_b Wt^T                     (k5)
//   W2t_b = (Wt^T - Wv^T P_b)^T as bf16 hi/lo ; b2_b = bt - bv^T P_b  (k6,k6b)
//   t_b  = X_b W2_b + b2_b             (k7: bf16 MFMA hi/lo 3-product ~ fp32 precision)
//   BN stats (k8); out = x + relu(...) (k9)
// ============================================================================

#define B_ 16
#define N_ 4096
#define C_ 256
#define M_ (B_*N_)
#define TS 64
#define PAD 68
#define BN_EPS 1e-5f

// ---- ws layout (float offsets), total 8393728 floats ~= 33.6 MB (same as R1) ----
#define OFF_GP   ((size_t)0)        // 4 slabs * 16 b * 256*256 fp32 partial Grams
#define OFF_T    ((size_t)4194304)
#define OFF_E    ((size_t)5242880)  // E, then A in-place
#define OFF_P    ((size_t)6291456)
#define OFF_W2   ((size_t)7340032)  // W2t hi bf16 [16][256][256] then W2t lo (2 MB each)
#define OFF_B2   ((size_t)8388608)
#define OFF_BNS  ((size_t)8392704)
#define OFF_BNQ  ((size_t)8392960)
#define OFF_MEAN ((size_t)8393216)
#define OFF_ISTD ((size_t)8393472)

typedef unsigned short u16;
typedef unsigned int u32;
typedef __attribute__((ext_vector_type(8))) short bf16x8;
typedef __attribute__((ext_vector_type(4))) float f32x4;
typedef __attribute__((ext_vector_type(8))) unsigned short u16x8;
typedef __attribute__((ext_vector_type(4))) unsigned short u16x4;

__device__ __forceinline__ u16 bf16_rn(float x) {
  u32 b = __float_as_uint(x);
  b += 0x7FFFu + ((b >> 16) & 1u);
  return (u16)(b >> 16);
}
__device__ __forceinline__ float bf16_tof(u16 h) {
  return __uint_as_float(((u32)h) << 16);
}

// ---------------- fp32 vector microkernel (kept for the tiny 256^3 chain) ---
__device__ __forceinline__ void load_tile_N(const float* __restrict__ src, int r0, int c0,
                                            float (*lds)[PAD], int t) {
#pragma unroll
  for (int p = 0; p < 4; ++p) {
    int slot = t + (p << 8);
    int r = slot >> 4, c4 = (slot & 15) << 2;
    *(float4*)&lds[r][c4] = *(const float4*)(src + (size_t)(r0 + r) * C_ + c0 + c4);
  }
}
__device__ __forceinline__ void load_tile_T(const float* __restrict__ src, int r0, int c0,
                                            float (*lds)[PAD], int t) {
#pragma unroll
  for (int p = 0; p < 4; ++p) {
    int slot = t + (p << 8);
    int r = slot >> 4, c4 = (slot & 15) << 2;
    float4 v = *(const float4*)(src + (size_t)(r0 + r) * C_ + c0 + c4);
    lds[c4 + 0][r] = v.x;
    lds[c4 + 1][r] = v.y;
    lds[c4 + 2][r] = v.z;
    lds[c4 + 3][r] = v.w;
  }
}
__device__ __forceinline__ void mk64(const float (*Al)[PAD], const float (*Bl)[PAD],
                                     int tr, int tc, float acc[4][4]) {
#pragma unroll 8
  for (int kk = 0; kk < TS; ++kk) {
    float4 a = *(const float4*)&Al[kk][tr << 2];
    float4 b = *(const float4*)&Bl[kk][tc << 2];
    acc[0][0] = fmaf(a.x, b.x, acc[0][0]); acc[0][1] = fmaf(a.x, b.y, acc[0][1]);
    acc[0][2] = fmaf(a.x, b.z, acc[0][2]); acc[0][3] = fmaf(a.x, b.w, acc[0][3]);
    acc[1][0] = fmaf(a.y, b.x, acc[1][0]); acc[1][1] = fmaf(a.y, b.y, acc[1][1]);
    acc[1][2] = fmaf(a.y, b.z, acc[1][2]); acc[1][3] = fmaf(a.y, b.w, acc[1][3]);
    acc[2][0] = fmaf(a.z, b.x, acc[2][0]); acc[2][1] = fmaf(a.z, b.y, acc[2][1]);
    acc[2][2] = fmaf(a.z, b.z, acc[2][2]); acc[2][3] = fmaf(a.z, b.w, acc[2][3]);
    acc[3][0] = fmaf(a.w, b.x, acc[3][0]); acc[3][1] = fmaf(a.w, b.y, acc[3][1]);
    acc[3][2] = fmaf(a.w, b.z, acc[3][2]); acc[3][3] = fmaf(a.w, b.w, acc[3][3]);
  }
}

// ---------------- k0: zero BN accumulators ----------------------------------
__global__ void k0_zero(float* __restrict__ ws) {
  ws[OFF_BNS + threadIdx.x] = 0.0f;  // 512 threads cover BNS(256)+BNQ(256)
}

// ---------------- k1: Gram via bf16 MFMA -------------------------------------
// Transposed staging: lds[c][nn] = bf16(X[n0+nn][c0+c]), XOR-swizzled.
__device__ __forceinline__ void stage_tr(const float* __restrict__ xb, int n0, int c0,
                                         u16* __restrict__ lds, int t) {
#pragma unroll
  for (int p = 0; p < 2; ++p) {
    int u = t + (p << 8);
    int n4 = u >> 5, c4 = u & 31;
    float4 row[4];
#pragma unroll
    for (int j = 0; j < 4; ++j)
      row[j] = *(const float4*)(xb + (size_t)(n0 + n4 * 4 + j) * C_ + c0 + c4 * 4);
#pragma unroll
    for (int i = 0; i < 4; ++i) {
      int c = c4 * 4 + i;
      u16x4 v;
#pragma unroll
      for (int j = 0; j < 4; ++j) v[j] = bf16_rn(((const float*)&row[j])[i]);
      int li = c * 64 + ((n4 * 4) ^ ((c & 7) * 8));
      *(u16x4*)&lds[li] = v;
    }
  }
}

__global__ __launch_bounds__(256, 2) void k1_mfma(const float* __restrict__ x,
                                                  float* __restrict__ ws) {
  const int idx3 = blockIdx.x, s = blockIdx.y, b = blockIdx.z;
  const int te = idx3 >> 1, tf = (idx3 + 1) >> 1;  // 0->(0,0) 1->(0,1) 2->(1,1)
  const int e0 = te * 128, f0 = tf * 128;
  const int t = threadIdx.x, lane = t & 63, w = t >> 6, wm = w >> 1, wn = w & 1;
  __shared__ u16 Ea[8192], Fa[8192];
  const float* xb = x + (size_t)b * N_ * C_;
  f32x4 acc[4][4] = {};
  for (int it = 0; it < 16; ++it) {
    const int n0 = (s << 10) + (it << 6);
    stage_tr(xb, n0, e0, Ea, t);
    if (e0 != f0) stage_tr(xb, n0, f0, Fa, t);
    __syncthreads();
    const u16* Bt = (e0 != f0) ? Fa : Ea;
#pragma unroll
    for (int kk = 0; kk < 64; kk += 32) {
      bf16x8 af[4], bfr[4];
#pragma unroll
      for (int mi = 0; mi < 4; ++mi) {
        int row = wm * 64 + mi * 16 + (lane & 15);
        int li = row * 64 + (((kk + 8 * (lane >> 4))) ^ ((row & 7) * 8));
        af[mi] = *(const bf16x8*)&Ea[li];
      }
#pragma unroll
      for (int ni = 0; ni < 4; ++ni) {
        int row = wn * 64 + ni * 16 + (lane & 15);
        int li = row * 64 + (((kk + 8 * (lane >> 4))) ^ ((row & 7) * 8));
        bfr[ni] = *(const bf16x8*)&Bt[li];
      }
#pragma unroll
      for (int mi = 0; mi < 4; ++mi)
#pragma unroll
        for (int ni = 0; ni < 4; ++ni)
          acc[mi][ni] = __builtin_amdgcn_mfma_f32_16x16x32_bf16(af[mi], bfr[ni], acc[mi][ni], 0, 0, 0);
    }
    __syncthreads();
  }
  float* gp = ws + OFF_GP + ((size_t)s * B_ + b) * (C_ * C_);
#pragma unroll
  for (int mi = 0; mi < 4; ++mi)
#pragma unroll
    for (int ni = 0; ni < 4; ++ni)
#pragma unroll
      for (int j = 0; j < 4; ++j) {
        int e = e0 + wm * 64 + mi * 16 + 4 * (lane >> 4) + j;
        int f = f0 + wn * 64 + ni * 16 + (lane & 15);
        float v = acc[mi][ni][j];
        gp[(size_t)e * C_ + f] = v;
        if (e0 != f0) gp[(size_t)f * C_ + e] = v;
      }
}

// ---------------- k2: T = G * Wq^T  (sum of 4 partial Grams) ----------------
__global__ __launch_bounds__(256) void k2_T(const float* __restrict__ Wq,
                                            float* __restrict__ ws) {
  const int tile = blockIdx.x, b = blockIdx.y;
  const int e0 = (tile >> 2) * TS, d0 = (tile & 3) * TS;
  const int t = threadIdx.x, tr = t >> 4, tc = t & 15;
  __shared__ float Al[TS][PAD], Bl[TS][PAD];
  float acc[4][4] = {};
  const float* gp = ws + OFF_GP + (size_t)b * (C_ * C_);
  for (int k0 = 0; k0 < C_; k0 += TS) {
#pragma unroll
    for (int p = 0; p < 4; ++p) {
      int slot = t + (p << 8);
      int r = slot >> 4, c4 = (slot & 15) << 2;
      size_t off = (size_t)(k0 + r) * C_ + e0 + c4;
      float4 v0 = *(const float4*)(gp + off);
      float4 v1 = *(const float4*)(gp + 1048576 + off);
      float4 v2 = *(const float4*)(gp + 2097152 + off);
      float4 v3 = *(const float4*)(gp + 3145728 + off);
      float4 v = make_float4(v0.x + v1.x + v2.x + v3.x, v0.y + v1.y + v2.y + v3.y,
                             v0.z + v1.z + v2.z + v3.z, v0.w + v1.w + v2.w + v3.w);
      *(float4*)&Al[r][c4] = v;
    }
    load_tile_T(Wq, d0, k0, Bl, t);
    __syncthreads();
    mk64(Al, Bl, tr, tc, acc);
    __syncthreads();
  }
  float* T = ws + OFF_T + ((size_t)b << 16);
#pragma unroll
  for (int i = 0; i < 4; ++i) {
    float4 v = make_float4(acc[i][0], acc[i][1], acc[i][2], acc[i][3]);
    *(float4*)(T + (size_t)(e0 + (tr << 2) + i) * C_ + d0 + (tc << 2)) = v;
  }
}

// ---------------- k3: E = Wq * T --------------------------------------------
__global__ __launch_bounds__(256) void k3_E(const float* __restrict__ Wq,
                                            float* __restrict__ ws) {
  const int tile = blockIdx.x, b = blockIdx.y;
  const int c0 = (tile >> 2) * TS, d0 = (tile & 3) * TS;
  const int t = threadIdx.x, tr = t >> 4, tc = t & 15;
  __shared__ float Al[TS][PAD], Bl[TS][PAD];
  float acc[4][4] = {};
  const float* T = ws + OFF_T + ((size_t)b << 16);
  for (int k0 = 0; k0 < C_; k0 += TS) {
    load_tile_T(Wq, c0, k0, Al, t);
    load_tile_N(T, k0, d0, Bl, t);
    __syncthreads();
    mk64(Al, Bl, tr, tc, acc);
    __syncthreads();
  }
  float* E = ws + OFF_E + ((size_t)b << 16);
#pragma unroll
  for (int i = 0; i < 4; ++i) {
    float4 v = make_float4(acc[i][0], acc[i][1], acc[i][2], acc[i][3]);
    *(float4*)(E + (size_t)(c0 + (tr << 2) + i) * C_ + d0 + (tc << 2)) = v;
  }
}

// ---------------- k4a: row softmax ------------------------------------------
__global__ __launch_bounds__(256) void k4a_softmax(float* __restrict__ E) {
  const int row = blockIdx.x, b = blockIdx.y;
  float* e = E + ((size_t)b << 16) + (size_t)row * C_;
  const int t = threadIdx.x, lane = t & 63, wid = t >> 6;
  __shared__ float rmax[4], rsum[4];
  float v = e[t];
  float m = v;
#pragma unroll
  for (int off = 32; off; off >>= 1) m = fmaxf(m, __shfl_xor(m, off, 64));
  if (lane == 0) rmax[wid] = m;
  __syncthreads();
  m = fmaxf(fmaxf(rmax[0], rmax[1]), fmaxf(rmax[2], rmax[3]));
  float ex = expf(v - m);
  float s = ex;
#pragma unroll
  for (int off = 32; off; off >>= 1) s += __shfl_xor(s, off, 64);
  if (lane == 0) rsum[wid] = s;
  __syncthreads();
  s = rsum[0] + rsum[1] + rsum[2] + rsum[3];
  e[t] = ex / s;
}

// ---------------- k4b: L1 normalize along columns ---------------------------
__global__ __launch_bounds__(256) void k4b_l1(float* __restrict__ A) {
  const int b = blockIdx.x, d = threadIdx.x;
  float* a = A + ((size_t)b << 16);
  float s = 0.0f;
  for (int c = 0; c < C_; ++c) s += a[(size_t)c * C_ + d];
  float inv = 1.0f / (1e-9f + s);
  for (int c = 0; c < C_; ++c) a[(size_t)c * C_ + d] *= inv;
}

// ---------------- k5: P = A * Wt^T ------------------------------------------
__global__ __launch_bounds__(256) void k5_P(const float* __restrict__ Wt,
                                            float* __restrict__ ws) {
  const int tile = blockIdx.x, b = blockIdx.y;
  const int c0 = (tile >> 2) * TS, o0 = (tile & 3) * TS;
  const int t = threadIdx.x, tr = t >> 4, tc = t & 15;
  __shared__ float Al[TS][PAD], Bl[TS][PAD];
  float acc[4][4] = {};
  const float* A = ws + OFF_E + ((size_t)b << 16);
  for (int k0 = 0; k0 < C_; k0 += TS) {
    load_tile_T(A, c0, k0, Al, t);
    load_tile_T(Wt, o0, k0, Bl, t);
    __syncthreads();
    mk64(Al, Bl, tr, tc, acc);
    __syncthreads();
  }
  float* P = ws + OFF_P + ((size_t)b << 16);
#pragma unroll
  for (int i = 0; i < 4; ++i) {
    float4 v = make_float4(acc[i][0], acc[i][1], acc[i][2], acc[i][3]);
    *(float4*)(P + (size_t)(c0 + (tr << 2) + i) * C_ + o0 + (tc << 2)) = v;
  }
}

// ---------------- k6: W2t = (Wt^T - Wv^T P)^T as bf16 hi/lo ------------------
__global__ __launch_bounds__(256) void k6_W2(const float* __restrict__ Wv,
                                             const float* __restrict__ Wt,
                                             float* __restrict__ ws) {
  const int tile = blockIdx.x, b = blockIdx.y;
  const int e0 = (tile >> 2) * TS, o0 = (tile & 3) * TS;
  const int t = threadIdx.x, tr = t >> 4, tc = t & 15;
  __shared__ float Al[TS][PAD], Bl[TS][PAD];
  float acc[4][4] = {};
  const float* P = ws + OFF_P + ((size_t)b << 16);
  for (int k0 = 0; k0 < C_; k0 += TS) {
    load_tile_N(Wv, k0, e0, Al, t);
    load_tile_N(P, k0, o0, Bl, t);
    __syncthreads();
    mk64(Al, Bl, tr, tc, acc);
    __syncthreads();
  }
  u16* W2H = (u16*)(ws + OFF_W2) + ((size_t)b << 16);
  u16* W2L = (u16*)(ws + OFF_W2) + 1048576 + ((size_t)b << 16);
#pragma unroll
  for (int i = 0; i < 4; ++i) {
    int e = e0 + (tr << 2) + i;
#pragma unroll
    for (int j = 0; j < 4; ++j) {
      int o = o0 + (tc << 2) + j;
      float wv = Wt[(size_t)o * C_ + e] - acc[i][j];
      u16 h = bf16_rn(wv);
      W2H[(size_t)o * C_ + e] = h;
      W2L[(size_t)o * C_ + e] = bf16_rn(wv - bf16_tof(h));
    }
  }
}

// ---------------- k6b: b2 = bt - bv^T * P -----------------------------------
__global__ __launch_bounds__(256) void k6b_b2(const float* __restrict__ bv,
                                              const float* __restrict__ bt,
                                              float* __restrict__ ws) {
  const int b = blockIdx.x, o = threadIdx.x;
  const float* P = ws + OFF_P + ((size_t)b << 16);
  float s = 0.0f;
  for (int c = 0; c < C_; ++c) s += bv[c] * P[(size_t)c * C_ + o];
  ws[OFF_B2 + (size_t)b * C_ + o] = bt[o] - s;
}

// ---------------- k7: t = X*W2 + b2 via bf16 MFMA hi/lo, + BN partials ------
__device__ __forceinline__ void cvt_hl8(const float* __restrict__ s, u16x8& h8, u16x8& l8) {
  float4 u0 = *(const float4*)s;
  float4 u1 = *(const float4*)(s + 4);
  float v[8] = {u0.x, u0.y, u0.z, u0.w, u1.x, u1.y, u1.z, u1.w};
#pragma unroll
  for (int i = 0; i < 8; ++i) {
    u16 h = bf16_rn(v[i]);
    h8[i] = h;
    l8[i] = bf16_rn(v[i] - bf16_tof(h));
  }
}

__global__ __launch_bounds__(256, 2) void k7_mfma(const float* __restrict__ x,
                                                  float* __restrict__ ws,
                                                  float* __restrict__ tout) {
  const int o0 = blockIdx.x * 128, n0 = blockIdx.y * 128, b = blockIdx.z;
  const int t = threadIdx.x, lane = t & 63, w = t >> 6, wm = w >> 1, wn = w & 1;
  __shared__ u16 Ah[8192], Al[8192], Bh[8192], Bl[8192];
  const float* xb = x + ((size_t)b * N_ + n0) * C_;
  const u16* W2Hb = (const u16*)(ws + OFF_W2) + ((size_t)b << 16) + (size_t)o0 * C_;
  const u16* W2Lb = (const u16*)(ws + OFF_W2) + 1048576 + ((size_t)b << 16) + (size_t)o0 * C_;
  f32x4 acc[4][4] = {};
  for (int k0 = 0; k0 < C_; k0 += 64) {
#pragma unroll
    for (int p = 0; p < 4; ++p) {
      int chunk = t + (p << 8);
      int r = chunk >> 3, k8 = chunk & 7;
      int li = r * 64 + ((k8 * 8) ^ ((r & 7) * 8));
      u16x8 h, l;
      cvt_hl8(xb + (size_t)r * C_ + k0 + k8 * 8, h, l);
      *(u16x8*)&Ah[li] = h;
      *(u16x8*)&Al[li] = l;
      *(u16x8*)&Bh[li] = *(const u16x8*)(W2Hb + (size_t)r * C_ + k0 + k8 * 8);
      *(u16x8*)&Bl[li] = *(const u16x8*)(W2Lb + (size_t)r * C_ + k0 + k8 * 8);
    }
    __syncthreads();
#pragma unroll
    for (int kk = 0; kk < 64; kk += 32) {
      bf16x8 ah[4], al[4], bh[4], bl[4];
#pragma unroll
      for (int mi = 0; mi < 4; ++mi) {
        int row = wm * 64 + mi * 16 + (lane & 15);
        int li = row * 64 + ((kk + 8 * (lane >> 4)) ^ ((row & 7) * 8));
        ah[mi] = *(const bf16x8*)&Ah[li];
        al[mi] = *(const bf16x8*)&Al[li];
      }
#pragma unroll
      for (int ni = 0; ni < 4; ++ni) {
        int row = wn * 64 + ni * 16 + (lane & 15);
        int li = row * 64 + ((kk + 8 * (lane >> 4)) ^ ((row & 7) * 8));
        bh[ni] = *(const bf16x8*)&Bh[li];
        bl[ni] = *(const bf16x8*)&Bl[li];
      }
#pragma unroll
      for (int mi = 0; mi < 4; ++mi)
#pragma unroll
        for (int ni = 0; ni < 4; ++ni) {
          acc[mi][ni] = __builtin_amdgcn_mfma_f32_16x16x32_bf16(ah[mi], bh[ni], acc[mi][ni], 0, 0, 0);
          acc[mi][ni] = __builtin_amdgcn_mfma_f32_16x16x32_bf16(al[mi], bh[ni], acc[mi][ni], 0, 0, 0);
          acc[mi][ni] = __builtin_amdgcn_mfma_f32_16x16x32_bf16(ah[mi], bl[ni], acc[mi][ni], 0, 0, 0);
        }
    }
    __syncthreads();
  }
  // epilogue: add b2, store t (fp32), accumulate BN partial sums
  const float* b2p = ws + OFF_B2 + (size_t)b * C_;
  float bb[4];
#pragma unroll
  for (int ni = 0; ni < 4; ++ni) bb[ni] = b2p[o0 + wn * 64 + ni * 16 + (lane & 15)];
  float cs[4] = {}, cq[4] = {};
#pragma unroll
  for (int mi = 0; mi < 4; ++mi) {
    int n = n0 + wm * 64 + mi * 16 + 4 * (lane >> 4);
#pragma unroll
    for (int ni = 0; ni < 4; ++ni) {
      int o = o0 + wn * 64 + ni * 16 + (lane & 15);
      float* outp = tout + ((size_t)b * N_ + n) * C_ + o;
#pragma unroll
      for (int j = 0; j < 4; ++j) {
        float val = acc[mi][ni][j] + bb[ni];
        outp[(size_t)j * C_] = val;
        cs[ni] += val;
        cq[ni] += val * val;
      }
    }
  }
#pragma unroll
  for (int ni = 0; ni < 4; ++ni) {
    float s = cs[ni], q = cq[ni];
    s += __shfl_xor(s, 16, 64); s += __shfl_xor(s, 32, 64);
    q += __shfl_xor(q, 16, 64); q += __shfl_xor(q, 32, 64);
    if ((lane >> 4) == 0) {
      atomicAdd(ws + OFF_BNS + o0 + wn * 64 + ni * 16 + lane, s);
      atomicAdd(ws + OFF_BNQ + o0 + wn * 64 + ni * 16 + lane, q);
    }
  }
}

// ---------------- k8: BN stats ----------------------------------------------
__global__ void k8_stats(float* __restrict__ ws) {
  const int c = threadIdx.x;
  float mean = ws[OFF_BNS + c] * (1.0f / (float)M_);
  float var = ws[OFF_BNQ + c] * (1.0f / (float)M_) - mean * mean;
  ws[OFF_MEAN + c] = mean;
  ws[OFF_ISTD + c] = rsqrtf(var + BN_EPS);
}

// ---------------- k9: out = x + relu(gamma*(t-mean)*istd + beta) ------------
__global__ __launch_bounds__(256) void k9_final(const float* __restrict__ x,
                                                const float* __restrict__ gamma,
                                                const float* __restrict__ beta,
                                                const float* __restrict__ ws,
                                                float* __restrict__ out) {
  const size_t i4 = ((size_t)blockIdx.x * 256 + threadIdx.x) << 2;
  const int c0 = (int)(i4 & 255);
  float4 tv = *(const float4*)(out + i4);
  float4 xv = *(const float4*)(x + i4);
  float4 g = *(const float4*)(gamma + c0);
  float4 be = *(const float4*)(beta + c0);
  float4 mn = *(const float4*)(ws + OFF_MEAN + c0);
  float4 is = *(const float4*)(ws + OFF_ISTD + c0);
  float4 r;
  r.x = xv.x + fmaxf(0.0f, fmaf(g.x, (tv.x - mn.x) * is.x, be.x));
  r.y = xv.y + fmaxf(0.0f, fmaf(g.y, (tv.y - mn.y) * is.y, be.y));
  r.z = xv.z + fmaxf(0.0f, fmaf(g.z, (tv.z - mn.z) * is.z, be.z));
  r.w = xv.w + fmaxf(0.0f, fmaf(g.w, (tv.w - mn.w) * is.w, be.w));
  *(float4*)(out + i4) = r;
}

// ============================================================================
extern "C" void kernel_launch(void* const* d_in, const int* in_sizes, int n_in,
                              void* d_out, int out_size, void* d_ws, size_t ws_size,
                              hipStream_t stream) {
  const float* x = (const float*)d_in[1];   // d_in[0] = xyz, unused by reference
  const float* Wq = (const float*)d_in[2];
  const float* Wv = (const float*)d_in[3];
  const float* bv = (const float*)d_in[4];
  const float* Wt = (const float*)d_in[5];
  const float* bt = (const float*)d_in[6];
  const float* gamma = (const float*)d_in[7];
  const float* beta = (const float*)d_in[8];
  float* out = (float*)d_out;
  float* ws = (float*)d_ws;

  k0_zero<<<1, 512, 0, stream>>>(ws);
  k1_mfma<<<dim3(3, 4, B_), 256, 0, stream>>>(x, ws);
  k2_T<<<dim3(16, B_), 256, 0, stream>>>(Wq, ws);
  k3_E<<<dim3(16, B_), 256, 0, stream>>>(Wq, ws);
  k4a_softmax<<<dim3(C_, B_), 256, 0, stream>>>(ws + OFF_E);
  k4b_l1<<<B_, 256, 0, stream>>>(ws + OFF_E);
  k5_P<<<dim3(16, B_), 256, 0, stream>>>(Wt, ws);
  k6_W2<<<dim3(16, B_), 256, 0, stream>>>(Wv, Wt, ws);
  k6b_b2<<<B_, 256, 0, stream>>>(bv, bt, ws);
  k7_mfma<<<dim3(2, 32, B_), 256, 0, stream>>>(x, ws, out);
  k8_stats<<<1, 256, 0, stream>>>(ws);
  k9_final<<<(M_ * C_) / 1024, 256, 0, stream>>>(x, gamma, beta, ws, out);
}